// Round 1
// baseline (3040.560 us; speedup 1.0000x reference)
//
#include <hip/hip_runtime.h>
#include <hip/hip_bf16.h>
#include <math.h>

// Problem constants (from reference): B=2, T=2048, M=1024, H=8, D=128
#define B_  2
#define T_  2048
#define M_  1024
#define H_  8
#define D_  128
#define NROW (B_ * T_)          // 4096 rows of flattened (b,t)
#define HD  (H_ * D_)           // 1024 cols of flattened (h,d)

#define NORM_EPS 1e-6f
#define QK_MULT  0.08838834764831845f   // sqrt(1/128)
#define ROT_BASE 10000.0f

// ---------------------------------------------------------------------------
// GEMM: C[NROW x 1024] = A[NROW x 1024] * B[1024 x 1024], all row-major fp32.
// 64x64 tile, 256 threads, 4x4 microtile, K-tile 16.
// ---------------------------------------------------------------------------
__global__ __launch_bounds__(256) void gemm_nn(const float* __restrict__ A,
                                               const float* __restrict__ Bm,
                                               float* __restrict__ C)
{
    __shared__ float As[16][64];   // [k][n]
    __shared__ float Bs[16][64];   // [k][p]

    const int tid = threadIdx.x;
    const int tx = tid & 15;       // col group (4 cols each)
    const int ty = tid >> 4;       // row group (4 rows each)
    const int n0 = blockIdx.y * 64;
    const int p0 = blockIdx.x * 64;

    const int ar = tid >> 2;           // 0..63  A-tile row
    const int ac = (tid & 3) << 2;     // 0,4,8,12
    const int br = tid >> 4;           // 0..15  B-tile row
    const int bc = (tid & 15) << 2;    // 0..60

    float acc[4][4] = {{0.f,0.f,0.f,0.f},{0.f,0.f,0.f,0.f},
                       {0.f,0.f,0.f,0.f},{0.f,0.f,0.f,0.f}};

    for (int k0 = 0; k0 < 1024; k0 += 16) {
        const float4 a4 = *(const float4*)(A  + (size_t)(n0 + ar) * 1024 + k0 + ac);
        const float4 b4 = *(const float4*)(Bm + (size_t)(k0 + br) * 1024 + p0 + bc);
        __syncthreads();   // protect previous iteration's LDS reads
        As[ac + 0][ar] = a4.x;
        As[ac + 1][ar] = a4.y;
        As[ac + 2][ar] = a4.z;
        As[ac + 3][ar] = a4.w;
        *(float4*)&Bs[br][bc] = b4;
        __syncthreads();
        #pragma unroll
        for (int kk = 0; kk < 16; ++kk) {
            const float4 av = *(const float4*)&As[kk][ty * 4];
            const float4 bv = *(const float4*)&Bs[kk][tx * 4];
            const float a[4] = {av.x, av.y, av.z, av.w};
            const float b[4] = {bv.x, bv.y, bv.z, bv.w};
            #pragma unroll
            for (int i2 = 0; i2 < 4; ++i2)
                #pragma unroll
                for (int j2 = 0; j2 < 4; ++j2)
                    acc[i2][j2] = fmaf(a[i2], b[j2], acc[i2][j2]);
        }
    }

    #pragma unroll
    for (int i2 = 0; i2 < 4; ++i2) {
        float4 o4 = make_float4(acc[i2][0], acc[i2][1], acc[i2][2], acc[i2][3]);
        *(float4*)(C + (size_t)(n0 + ty * 4 + i2) * 1024 + p0 + tx * 4) = o4;
    }
}

// ---------------------------------------------------------------------------
// Fused RMSNorm (over d=128, no gains) + RoPE + sqrt(qk_scale) fold.
// One 64-lane wave per (b,t,h) vector. blockIdx.y: 0 -> q, 1 -> k.
// Layout of q/k: [b,t,h,d] contiguous (row-major [NROW][HD]).
// ---------------------------------------------------------------------------
__global__ __launch_bounds__(64) void rmsnorm_rope(float* __restrict__ q,
                                                   float* __restrict__ k)
{
    const int vec = blockIdx.x;                 // (b*T + t)*H + h
    float* p = (blockIdx.y == 0 ? q : k) + (size_t)vec * 128;
    const int t = (vec / H_) % T_;
    const int lane = threadIdx.x;               // 0..63

    float e = p[lane];
    float o = p[lane + 64];
    float ss = e * e + o * o;
    #pragma unroll
    for (int off = 32; off; off >>= 1) ss += __shfl_xor(ss, off);
    const float r = rsqrtf(ss * (1.0f / 128.0f) + NORM_EPS) * QK_MULT;
    e *= r;
    o *= r;

    // freqs[lane] = base^(-lane/64); rad = t * freq
    const float freq = expf(-(float)lane * (logf(ROT_BASE) / 64.0f));
    const float rad = (float)t * freq;
    const float c = cosf(rad);
    const float s = sinf(rad);

    p[lane]      = e * c - o * s;
    p[lane + 64] = e * s + o * c;
}

// ---------------------------------------------------------------------------
// Causal attention, one 256-thread block per (b,h,i) row.
// q,k,v,o all in [b,t,h,d] layout. Scale already folded into q,k.
// ---------------------------------------------------------------------------
__global__ __launch_bounds__(256) void attn_row(const float* __restrict__ q,
                                                const float* __restrict__ k,
                                                const float* __restrict__ v,
                                                float* __restrict__ o)
{
    __shared__ float sbuf[T_];     // scores -> probs
    __shared__ float qs[128];
    __shared__ float red[4];

    const int bid = blockIdx.x;            // ((b*H)+h)*T + i
    const int i  = bid % T_;
    const int bh = bid / T_;
    const int h  = bh % H_;
    const int b  = bh / H_;
    const int tid = threadIdx.x;

    const size_t rowQ = ((size_t)(b * T_ + i) * H_ + h) * 128;
    if (tid < 128) qs[tid] = q[rowQ + tid];
    __syncthreads();

    // --- scores s_j = q . k_j  for j <= i ---
    float lmax = -1e30f;
    for (int j = tid; j <= i; j += 256) {
        const float* kr = k + ((size_t)(b * T_ + j) * H_ + h) * 128;
        float dot = 0.f;
        #pragma unroll
        for (int d = 0; d < 128; d += 4) {
            const float4 kv = *(const float4*)(kr + d);
            dot += qs[d] * kv.x + qs[d + 1] * kv.y + qs[d + 2] * kv.z + qs[d + 3] * kv.w;
        }
        sbuf[j] = dot;
        lmax = fmaxf(lmax, dot);
    }

    // --- block max ---
    #pragma unroll
    for (int off = 32; off; off >>= 1) lmax = fmaxf(lmax, __shfl_xor(lmax, off));
    if ((tid & 63) == 0) red[tid >> 6] = lmax;
    __syncthreads();
    const float mx = fmaxf(fmaxf(red[0], red[1]), fmaxf(red[2], red[3]));

    // --- exp + sum ---
    float lsum = 0.f;
    for (int j = tid; j <= i; j += 256) {
        const float pv = expf(sbuf[j] - mx);
        sbuf[j] = pv;
        lsum += pv;
    }
    #pragma unroll
    for (int off = 32; off; off >>= 1) lsum += __shfl_xor(lsum, off);
    __syncthreads();                 // mx reads + sbuf writes done
    if ((tid & 63) == 0) red[tid >> 6] = lsum;
    __syncthreads();
    const float l = red[0] + red[1] + red[2] + red[3];

    // --- O = (P . V) / l, threads 0..127 each own one d ---
    if (tid < 128) {
        float acc = 0.f;
        const float* vb = v + ((size_t)(b * T_) * H_ + h) * 128 + tid;  // stride 1024 per j
        int j = 0;
        for (; j + 4 <= i + 1; j += 4) {
            acc += sbuf[j]     * vb[(size_t)(j)     * 1024];
            acc += sbuf[j + 1] * vb[(size_t)(j + 1) * 1024];
            acc += sbuf[j + 2] * vb[(size_t)(j + 2) * 1024];
            acc += sbuf[j + 3] * vb[(size_t)(j + 3) * 1024];
        }
        for (; j <= i; ++j) acc += sbuf[j] * vb[(size_t)j * 1024];
        o[rowQ + tid] = acc / l;
    }
}

// ---------------------------------------------------------------------------
extern "C" void kernel_launch(void* const* d_in, const int* in_sizes, int n_in,
                              void* d_out, int out_size, void* d_ws, size_t ws_size,
                              hipStream_t stream)
{
    const float* x  = (const float*)d_in[0];   // [B,T,M]  = [4096,1024]
    const float* wq = (const float*)d_in[1];   // [M,H,D]  = [1024,1024]
    const float* wk = (const float*)d_in[2];
    const float* wv = (const float*)d_in[3];
    const float* wo = (const float*)d_in[4];   // [H,D,M]  = [1024,1024]
    float* out = (float*)d_out;                // [B,T,M]  fp32

    const size_t SZ = (size_t)NROW * HD;       // 4096*1024 floats
    float* q = (float*)d_ws;
    float* k = q + SZ;
    float* v = k + SZ;
    float* o = v + SZ;

    dim3 gemm_grid(1024 / 64, NROW / 64);      // (16, 64)
    gemm_nn<<<gemm_grid, 256, 0, stream>>>(x, wq, q);
    gemm_nn<<<gemm_grid, 256, 0, stream>>>(x, wk, k);
    gemm_nn<<<gemm_grid, 256, 0, stream>>>(x, wv, v);

    rmsnorm_rope<<<dim3(NROW * H_, 2), 64, 0, stream>>>(q, k);

    attn_row<<<B_ * H_ * T_, 256, 0, stream>>>(q, k, v, o);

    gemm_nn<<<gemm_grid, 256, 0, stream>>>(o, wo, out);
}

// Round 2
// 677.233 us; speedup vs baseline: 4.4897x; 4.4897x over previous
//
#include <hip/hip_runtime.h>
#include <hip/hip_bf16.h>
#include <math.h>

// Problem constants: B=2, T=2048, M=1024, H=8, D=128
#define B_  2
#define T_  2048
#define M_  1024
#define H_  8
#define D_  128
#define NROW (B_ * T_)          // 4096
#define HD  (H_ * D_)           // 1024

#define NORM_EPS 1e-6f
#define QK_MULT  0.08838834764831845f   // sqrt(1/128)
#define ROT_BASE 10000.0f

typedef short bf16x8 __attribute__((ext_vector_type(8)));   // 8 bf16 = 4 VGPRs
typedef float f32x4  __attribute__((ext_vector_type(4)));

static __device__ __forceinline__ unsigned short f2bf(float f) {
    union { __hip_bfloat16 h; unsigned short u; } cv;
    cv.h = __float2bfloat16(f);
    return cv.u;
}
static __device__ __forceinline__ float bf2f(unsigned short u) {
    union { unsigned short u; __hip_bfloat16 h; } cv;
    cv.u = u;
    return __bfloat162float(cv.h);
}

// ---------------------------------------------------------------------------
// GEMM: C[NROW x 1024] = A[NROW x 1024] * B[1024 x 1024], row-major fp32 in.
// Output fp32 or bf16 (template). 64x64 tile, 256 thr, 4x4 microtile.
// ---------------------------------------------------------------------------
template <bool BF16OUT>
__global__ __launch_bounds__(256) void gemm_nn_t(const float* __restrict__ A,
                                                 const float* __restrict__ Bm,
                                                 void* __restrict__ Cv)
{
    __shared__ float As[16][64];   // [k][n]
    __shared__ float Bs[16][64];   // [k][p]

    const int tid = threadIdx.x;
    const int tx = tid & 15;
    const int ty = tid >> 4;
    const int n0 = blockIdx.y * 64;
    const int p0 = blockIdx.x * 64;

    const int ar = tid >> 2;
    const int ac = (tid & 3) << 2;
    const int br = tid >> 4;
    const int bc = (tid & 15) << 2;

    float acc[4][4] = {{0.f,0.f,0.f,0.f},{0.f,0.f,0.f,0.f},
                       {0.f,0.f,0.f,0.f},{0.f,0.f,0.f,0.f}};

    for (int k0 = 0; k0 < 1024; k0 += 16) {
        const float4 a4 = *(const float4*)(A  + (size_t)(n0 + ar) * 1024 + k0 + ac);
        const float4 b4 = *(const float4*)(Bm + (size_t)(k0 + br) * 1024 + p0 + bc);
        __syncthreads();
        As[ac + 0][ar] = a4.x;
        As[ac + 1][ar] = a4.y;
        As[ac + 2][ar] = a4.z;
        As[ac + 3][ar] = a4.w;
        *(float4*)&Bs[br][bc] = b4;
        __syncthreads();
        #pragma unroll
        for (int kk = 0; kk < 16; ++kk) {
            const float4 av = *(const float4*)&As[kk][ty * 4];
            const float4 bv = *(const float4*)&Bs[kk][tx * 4];
            const float a[4] = {av.x, av.y, av.z, av.w};
            const float b[4] = {bv.x, bv.y, bv.z, bv.w};
            #pragma unroll
            for (int i2 = 0; i2 < 4; ++i2)
                #pragma unroll
                for (int j2 = 0; j2 < 4; ++j2)
                    acc[i2][j2] = fmaf(a[i2], b[j2], acc[i2][j2]);
        }
    }

    #pragma unroll
    for (int i2 = 0; i2 < 4; ++i2) {
        if (BF16OUT) {
            unsigned short* C = (unsigned short*)Cv;
            ushort4 o4;
            o4.x = f2bf(acc[i2][0]); o4.y = f2bf(acc[i2][1]);
            o4.z = f2bf(acc[i2][2]); o4.w = f2bf(acc[i2][3]);
            *(ushort4*)(C + (size_t)(n0 + ty * 4 + i2) * 1024 + p0 + tx * 4) = o4;
        } else {
            float* C = (float*)Cv;
            float4 o4 = make_float4(acc[i2][0], acc[i2][1], acc[i2][2], acc[i2][3]);
            *(float4*)(C + (size_t)(n0 + ty * 4 + i2) * 1024 + p0 + tx * 4) = o4;
        }
    }
}

// ---------------------------------------------------------------------------
// Fused RMSNorm + RoPE + sqrt(qk_scale), bf16 in-place. One wave per vector.
// ---------------------------------------------------------------------------
__global__ __launch_bounds__(64) void rmsnorm_rope_bf16(unsigned short* __restrict__ q,
                                                        unsigned short* __restrict__ k)
{
    const int vec = blockIdx.x;                 // (b*T + t)*H + h
    unsigned short* p = (blockIdx.y == 0 ? q : k) + (size_t)vec * 128;
    const int t = (vec / H_) % T_;
    const int lane = threadIdx.x;

    float e = bf2f(p[lane]);
    float o = bf2f(p[lane + 64]);
    float ss = e * e + o * o;
    #pragma unroll
    for (int off = 32; off; off >>= 1) ss += __shfl_xor(ss, off);
    const float r = rsqrtf(ss * (1.0f / 128.0f) + NORM_EPS) * QK_MULT;
    e *= r;
    o *= r;

    const float freq = expf(-(float)lane * (logf(ROT_BASE) / 64.0f));
    const float rad = (float)t * freq;
    const float c = cosf(rad);
    const float s = sinf(rad);

    p[lane]      = f2bf(e * c - o * s);
    p[lane + 64] = f2bf(e * s + o * c);
}

// ---------------------------------------------------------------------------
// Flash attention, bf16 MFMA. One 256-thr block per (b,h, q-tile of 64).
// Per wave: 16 q-rows. S = Q K^T via mfma 16x16x32; online softmax in
// C-layout regs; P -> LDS -> A-layout; O += P V via mfma. o written fp32.
// LDS strides in bf16 elements (rows 16B-aligned).
// ---------------------------------------------------------------------------
#define KLD 136   // 128 + 8
#define VLD 72    // 64 + 8
#define PLD 72    // 64 + 8

__global__ __launch_bounds__(256) void flash_attn(const unsigned short* __restrict__ qb,
                                                  const unsigned short* __restrict__ kb,
                                                  const unsigned short* __restrict__ vb,
                                                  float* __restrict__ o)
{
    __shared__ unsigned short Ks[64 * KLD];       // [j][d]
    __shared__ unsigned short Vt[128 * VLD];      // [d][j]  (transposed)
    __shared__ unsigned short Ps[4][16 * PLD];    // per-wave P tile [qi][j]

    const int tid  = threadIdx.x;
    const int lane = tid & 63;
    const int w    = tid >> 6;          // wave 0..3
    const int g    = lane >> 4;         // quad 0..3
    const int lc   = lane & 15;

    const int bh = blockIdx.x;          // b*H + h
    const int h  = bh & (H_ - 1);
    const int b  = bh >> 3;
    const int yy = blockIdx.y;
    const int qt = (yy & 1) ? (31 - (yy >> 1)) : (yy >> 1);   // load-balance swizzle
    const int q0 = qt * 64;

    const size_t bhbase = (size_t)b * T_ * HD + (size_t)h * 128;  // + t*1024 + d

    // Q fragments (A-operand): lane -> Q[q0+w*16+lc][dc*32 + g*8 .. +8]
    bf16x8 qf[4];
    {
        const unsigned short* qp = qb + bhbase + (size_t)(q0 + w * 16 + lc) * 1024 + g * 8;
        #pragma unroll
        for (int dc = 0; dc < 4; ++dc)
            qf[dc] = *(const bf16x8*)(qp + dc * 32);
    }

    float m_r[4], l_r[4];
    f32x4 oacc[8];
    #pragma unroll
    for (int r = 0; r < 4; ++r) { m_r[r] = -1e30f; l_r[r] = 0.f; }
    #pragma unroll
    for (int dc8 = 0; dc8 < 8; ++dc8) oacc[dc8] = (f32x4){0.f, 0.f, 0.f, 0.f};

    for (int jt = 0; jt <= qt; ++jt) {
        const int j0 = jt * 64;

        // --- stage K tile [64][128] ---
        #pragma unroll
        for (int it = 0; it < 4; ++it) {
            const int u = tid + it * 256;        // 0..1023
            const int row = u >> 4;
            const int seg = u & 15;              // 16B units
            bf16x8 kv = *(const bf16x8*)(kb + bhbase + (size_t)(j0 + row) * 1024 + seg * 8);
            *(bf16x8*)&Ks[row * KLD + seg * 8] = kv;
        }
        // --- stage V tile transposed -> Vt[d][j] ---
        #pragma unroll
        for (int it = 0; it < 4; ++it) {
            const int u = tid + it * 256;
            const int j  = u & 63;
            const int dg = u >> 6;               // 0..15 (8 d's each)
            bf16x8 vv = *(const bf16x8*)(vb + bhbase + (size_t)(j0 + j) * 1024 + dg * 8);
            #pragma unroll
            for (int i2 = 0; i2 < 8; ++i2)
                Vt[(dg * 8 + i2) * VLD + j] = (unsigned short)vv[i2];
        }
        __syncthreads();

        // --- S = Q K^T : 4 j-chunks x 4 d-steps ---
        f32x4 sacc[4];
        #pragma unroll
        for (int jc = 0; jc < 4; ++jc) {
            sacc[jc] = (f32x4){0.f, 0.f, 0.f, 0.f};
            #pragma unroll
            for (int dc = 0; dc < 4; ++dc) {
                bf16x8 bf = *(const bf16x8*)&Ks[(jc * 16 + lc) * KLD + dc * 32 + g * 8];
                sacc[jc] = __builtin_amdgcn_mfma_f32_16x16x32_bf16(qf[dc], bf, sacc[jc], 0, 0, 0);
            }
        }

        // --- causal mask on diagonal tile ---
        if (jt == qt) {
            const int qi = q0 + w * 16 + g * 4;
            #pragma unroll
            for (int jc = 0; jc < 4; ++jc) {
                const int jj = j0 + jc * 16 + lc;
                #pragma unroll
                for (int r = 0; r < 4; ++r)
                    if (qi + r < jj) sacc[jc][r] = -1e30f;
            }
        }

        // --- online softmax (row = g*4+r, 16 lanes per row-group) ---
        #pragma unroll
        for (int r = 0; r < 4; ++r) {
            float tmax = fmaxf(fmaxf(sacc[0][r], sacc[1][r]), fmaxf(sacc[2][r], sacc[3][r]));
            #pragma unroll
            for (int off = 1; off < 16; off <<= 1)
                tmax = fmaxf(tmax, __shfl_xor(tmax, off));
            const float mn = fmaxf(m_r[r], tmax);
            const float alpha = __expf(m_r[r] - mn);
            m_r[r] = mn;
            float rs = 0.f;
            #pragma unroll
            for (int jc = 0; jc < 4; ++jc) {
                const float p = __expf(sacc[jc][r] - mn);
                sacc[jc][r] = p;
                rs += p;
            }
            #pragma unroll
            for (int off = 1; off < 16; off <<= 1)
                rs += __shfl_xor(rs, off);
            l_r[r] = l_r[r] * alpha + rs;
            #pragma unroll
            for (int dc8 = 0; dc8 < 8; ++dc8)
                oacc[dc8][r] *= alpha;
        }

        // --- P (C-layout) -> LDS -> A-layout fragments (wave-private) ---
        unsigned short* pw = Ps[w];
        #pragma unroll
        for (int jc = 0; jc < 4; ++jc)
            #pragma unroll
            for (int r = 0; r < 4; ++r)
                pw[(g * 4 + r) * PLD + jc * 16 + lc] = f2bf(sacc[jc][r]);

        __asm__ volatile("s_waitcnt lgkmcnt(0)" ::: "memory");

        bf16x8 pa[2];
        #pragma unroll
        for (int jc2 = 0; jc2 < 2; ++jc2)
            pa[jc2] = *(const bf16x8*)&pw[lc * PLD + jc2 * 32 + g * 8];

        // --- O += P V : 8 d-chunks x 2 j-steps ---
        #pragma unroll
        for (int dc8 = 0; dc8 < 8; ++dc8) {
            #pragma unroll
            for (int jc2 = 0; jc2 < 2; ++jc2) {
                bf16x8 bv = *(const bf16x8*)&Vt[(dc8 * 16 + lc) * VLD + jc2 * 32 + g * 8];
                oacc[dc8] = __builtin_amdgcn_mfma_f32_16x16x32_bf16(pa[jc2], bv, oacc[dc8], 0, 0, 0);
            }
        }
        __syncthreads();
    }

    // --- epilogue: O /= l, write fp32 [b,t,h,d] ---
    #pragma unroll
    for (int r = 0; r < 4; ++r) {
        const float inv = 1.0f / l_r[r];
        float* op = o + bhbase + (size_t)(q0 + w * 16 + g * 4 + r) * 1024 + lc;
        #pragma unroll
        for (int dc8 = 0; dc8 < 8; ++dc8)
            op[dc8 * 16] = oacc[dc8][r] * inv;
    }
}

// ---------------------------------------------------------------------------
extern "C" void kernel_launch(void* const* d_in, const int* in_sizes, int n_in,
                              void* d_out, int out_size, void* d_ws, size_t ws_size,
                              hipStream_t stream)
{
    const float* x  = (const float*)d_in[0];   // [4096,1024]
    const float* wq = (const float*)d_in[1];
    const float* wk = (const float*)d_in[2];
    const float* wv = (const float*)d_in[3];
    const float* wo = (const float*)d_in[4];
    float* out = (float*)d_out;

    const size_t SZ = (size_t)NROW * HD;       // 4M elements
    unsigned short* qb = (unsigned short*)d_ws;        // 8 MB
    unsigned short* kb = qb + SZ;                      // 8 MB
    unsigned short* vb = kb + SZ;                      // 8 MB
    float* o = (float*)(vb + SZ);                      // 16 MB

    dim3 gemm_grid(1024 / 64, NROW / 64);
    gemm_nn_t<true><<<gemm_grid, 256, 0, stream>>>(x, wq, qb);
    gemm_nn_t<true><<<gemm_grid, 256, 0, stream>>>(x, wk, kb);
    gemm_nn_t<true><<<gemm_grid, 256, 0, stream>>>(x, wv, vb);

    rmsnorm_rope_bf16<<<dim3(NROW * H_, 2), 64, 0, stream>>>(qb, kb);

    flash_attn<<<dim3(B_ * H_, 32), 256, 0, stream>>>(qb, kb, vb, o);

    gemm_nn_t<false><<<gemm_grid, 256, 0, stream>>>(o, wo, out);
}

// Round 3
// 249.606 us; speedup vs baseline: 12.1814x; 2.7132x over previous
//
#include <hip/hip_runtime.h>
#include <hip/hip_bf16.h>
#include <math.h>

// Problem constants: B=2, T=2048, M=1024, H=8, D=128
#define B_  2
#define T_  2048
#define M_  1024
#define H_  8
#define D_  128
#define NROW (B_ * T_)          // 4096
#define HD  (H_ * D_)           // 1024

#define NORM_EPS 1e-6f
#define QK_MULT  0.08838834764831845f   // sqrt(1/128)
#define ROT_BASE 10000.0f

typedef short bf16x8 __attribute__((ext_vector_type(8)));   // 8 bf16 = 4 VGPRs
typedef float f32x4  __attribute__((ext_vector_type(4)));

static __device__ __forceinline__ unsigned short f2bf(float f) {
    union { __hip_bfloat16 h; unsigned short u; } cv;
    cv.h = __float2bfloat16(f);
    return cv.u;
}
static __device__ __forceinline__ float bf2f(unsigned short u) {
    union { unsigned short u; __hip_bfloat16 h; } cv;
    cv.u = u;
    return __bfloat162float(cv.h);
}

// async global->LDS, 16 bytes per lane. LDS dest must be wave-uniform base
// + lane*16 (m97-verified pattern).
static __device__ __forceinline__ void gload_lds16(const unsigned short* g,
                                                   unsigned short* l) {
    __builtin_amdgcn_global_load_lds(
        (const __attribute__((address_space(1))) void*)g,
        (__attribute__((address_space(3))) void*)l, 16, 0, 0);
}

// ---------------------------------------------------------------------------
// cast fp32 -> bf16, 4 elements/thread
// ---------------------------------------------------------------------------
__global__ __launch_bounds__(256) void cast_bf16(const float* __restrict__ in,
                                                 unsigned short* __restrict__ out)
{
    const int i = (blockIdx.x * 256 + threadIdx.x) * 4;
    const float4 v = *(const float4*)(in + i);
    ushort4 o;
    o.x = f2bf(v.x); o.y = f2bf(v.y); o.z = f2bf(v.z); o.w = f2bf(v.w);
    *(ushort4*)(out + i) = o;
}

// ---------------------------------------------------------------------------
// transpose + cast: out[n][k] = bf16(in[k][n]), 1024x1024, 32x32 tiles
// ---------------------------------------------------------------------------
__global__ __launch_bounds__(256) void transpose_cast(const float* __restrict__ in,
                                                      unsigned short* __restrict__ out)
{
    __shared__ float t[32][33];
    const int tx = threadIdx.x & 31;
    const int ty = threadIdx.x >> 5;          // 0..7
    const int n0 = blockIdx.x * 32;
    const int k0 = blockIdx.y * 32;
    #pragma unroll
    for (int r = 0; r < 4; ++r)
        t[ty + r * 8][tx] = in[(size_t)(k0 + ty + r * 8) * 1024 + n0 + tx];
    __syncthreads();
    #pragma unroll
    for (int r = 0; r < 4; ++r)
        out[(size_t)(n0 + ty + r * 8) * 1024 + k0 + tx] = f2bf(t[tx][ty + r * 8]);
}

// ---------------------------------------------------------------------------
// bf16 MFMA GEMM (m97 structure): C[M x N] = A[M x K] * Bt[N x K]^T
// K=1024. 128x128 tile, 256 thr (2x2 waves of 64x64), BK=32,
// global_load_lds width 16, unpadded LDS, ds_read_b128 frags.
// MODE 0: bf16 out, split across q/k/v by n>>10 (fused QKV, N=3072).
// MODE 1: fp32 out, single buffer (N=1024).
// ---------------------------------------------------------------------------
template <int MODE>
__global__ __launch_bounds__(256) void gemm_bt(const unsigned short* __restrict__ A,
                                               const unsigned short* __restrict__ Bt,
                                               unsigned short* __restrict__ oq,
                                               unsigned short* __restrict__ ok,
                                               unsigned short* __restrict__ ov,
                                               float* __restrict__ cf)
{
    __shared__ unsigned short As[128 * 32];
    __shared__ unsigned short Bs[128 * 32];

    const int tid  = threadIdx.x;
    const int lane = tid & 63;
    const int w    = tid >> 6;
    const int g    = lane >> 4;
    const int lc   = lane & 15;
    const int wm   = w >> 1;
    const int wn   = w & 1;

    const int m0 = blockIdx.y * 128;
    const int n0 = blockIdx.x * 128;

    const unsigned short* aBase = A  + (size_t)m0 * 1024;
    const unsigned short* bBase = Bt + (size_t)n0 * 1024;

    f32x4 acc[4][4];
    #pragma unroll
    for (int i = 0; i < 4; ++i)
        #pragma unroll
        for (int j = 0; j < 4; ++j)
            acc[i][j] = (f32x4){0.f, 0.f, 0.f, 0.f};

    for (int kt = 0; kt < 32; ++kt) {
        const int k0 = kt * 32;
        #pragma unroll
        for (int it = 0; it < 2; ++it) {
            const int u  = tid + it * 256;      // 0..511
            const int r2 = u >> 2;              // tile row
            const int s2 = u & 3;               // 16B segment in row
            gload_lds16(aBase + (size_t)r2 * 1024 + k0 + s2 * 8, &As[u * 8]);
            gload_lds16(bBase + (size_t)r2 * 1024 + k0 + s2 * 8, &Bs[u * 8]);
        }
        __syncthreads();

        bf16x8 af[4], bfr[4];
        #pragma unroll
        for (int i = 0; i < 4; ++i)
            af[i] = *(const bf16x8*)&As[(wm * 64 + i * 16 + lc) * 32 + g * 8];
        #pragma unroll
        for (int j = 0; j < 4; ++j)
            bfr[j] = *(const bf16x8*)&Bs[(wn * 64 + j * 16 + lc) * 32 + g * 8];

        #pragma unroll
        for (int i = 0; i < 4; ++i)
            #pragma unroll
            for (int j = 0; j < 4; ++j)
                acc[i][j] = __builtin_amdgcn_mfma_f32_16x16x32_bf16(af[i], bfr[j], acc[i][j], 0, 0, 0);
        __syncthreads();
    }

    if (MODE == 0) {
        const int which = n0 >> 10;
        unsigned short* outp = which == 0 ? oq : (which == 1 ? ok : ov);
        const int ncol0 = (n0 & 1023) + wn * 64;
        #pragma unroll
        for (int i = 0; i < 4; ++i) {
            const int mrow = m0 + wm * 64 + i * 16 + g * 4;
            #pragma unroll
            for (int j = 0; j < 4; ++j) {
                const int nc = ncol0 + j * 16 + lc;
                #pragma unroll
                for (int r = 0; r < 4; ++r)
                    outp[(size_t)(mrow + r) * 1024 + nc] = f2bf(acc[i][j][r]);
            }
        }
    } else {
        #pragma unroll
        for (int i = 0; i < 4; ++i) {
            const int mrow = m0 + wm * 64 + i * 16 + g * 4;
            #pragma unroll
            for (int j = 0; j < 4; ++j) {
                const int nc = n0 + wn * 64 + j * 16 + lc;
                #pragma unroll
                for (int r = 0; r < 4; ++r)
                    cf[(size_t)(mrow + r) * 1024 + nc] = acc[i][j][r];
            }
        }
    }
}

// ---------------------------------------------------------------------------
// Fused RMSNorm + RoPE + sqrt(qk_scale), bf16 in-place. One wave per vector.
// ---------------------------------------------------------------------------
__global__ __launch_bounds__(64) void rmsnorm_rope_bf16(unsigned short* __restrict__ q,
                                                        unsigned short* __restrict__ k)
{
    const int vec = blockIdx.x;                 // (b*T + t)*H + h
    unsigned short* p = (blockIdx.y == 0 ? q : k) + (size_t)vec * 128;
    const int t = (vec / H_) % T_;
    const int lane = threadIdx.x;

    float e = bf2f(p[lane]);
    float o = bf2f(p[lane + 64]);
    float ss = e * e + o * o;
    #pragma unroll
    for (int off = 32; off; off >>= 1) ss += __shfl_xor(ss, off);
    const float r = rsqrtf(ss * (1.0f / 128.0f) + NORM_EPS) * QK_MULT;
    e *= r;
    o *= r;

    const float freq = expf(-(float)lane * (logf(ROT_BASE) / 64.0f));
    const float rad = (float)t * freq;
    const float c = cosf(rad);
    const float s = sinf(rad);

    p[lane]      = f2bf(e * c - o * s);
    p[lane + 64] = f2bf(e * s + o * c);
}

// ---------------------------------------------------------------------------
// Flash attention, bf16 MFMA. One 256-thr block per (b,h, q-tile of 64).
// Output written bf16 (feeds the bf16 output GEMM).
// ---------------------------------------------------------------------------
#define KLD 136   // 128 + 8
#define VLD 72    // 64 + 8
#define PLD 72    // 64 + 8

__global__ __launch_bounds__(256) void flash_attn(const unsigned short* __restrict__ qb,
                                                  const unsigned short* __restrict__ kb,
                                                  const unsigned short* __restrict__ vb,
                                                  unsigned short* __restrict__ o)
{
    __shared__ unsigned short Ks[64 * KLD];       // [j][d]
    __shared__ unsigned short Vt[128 * VLD];      // [d][j]  (transposed)
    __shared__ unsigned short Ps[4][16 * PLD];    // per-wave P tile [qi][j]

    const int tid  = threadIdx.x;
    const int lane = tid & 63;
    const int w    = tid >> 6;
    const int g    = lane >> 4;
    const int lc   = lane & 15;

    const int bh = blockIdx.x;          // b*H + h
    const int h  = bh & (H_ - 1);
    const int b  = bh >> 3;
    const int yy = blockIdx.y;
    const int qt = (yy & 1) ? (31 - (yy >> 1)) : (yy >> 1);
    const int q0 = qt * 64;

    const size_t bhbase = (size_t)b * T_ * HD + (size_t)h * 128;

    bf16x8 qf[4];
    {
        const unsigned short* qp = qb + bhbase + (size_t)(q0 + w * 16 + lc) * 1024 + g * 8;
        #pragma unroll
        for (int dc = 0; dc < 4; ++dc)
            qf[dc] = *(const bf16x8*)(qp + dc * 32);
    }

    float m_r[4], l_r[4];
    f32x4 oacc[8];
    #pragma unroll
    for (int r = 0; r < 4; ++r) { m_r[r] = -1e30f; l_r[r] = 0.f; }
    #pragma unroll
    for (int dc8 = 0; dc8 < 8; ++dc8) oacc[dc8] = (f32x4){0.f, 0.f, 0.f, 0.f};

    for (int jt = 0; jt <= qt; ++jt) {
        const int j0 = jt * 64;

        #pragma unroll
        for (int it = 0; it < 4; ++it) {
            const int u = tid + it * 256;
            const int row = u >> 4;
            const int seg = u & 15;
            bf16x8 kv = *(const bf16x8*)(kb + bhbase + (size_t)(j0 + row) * 1024 + seg * 8);
            *(bf16x8*)&Ks[row * KLD + seg * 8] = kv;
        }
        #pragma unroll
        for (int it = 0; it < 4; ++it) {
            const int u = tid + it * 256;
            const int j  = u & 63;
            const int dg = u >> 6;
            bf16x8 vv = *(const bf16x8*)(vb + bhbase + (size_t)(j0 + j) * 1024 + dg * 8);
            #pragma unroll
            for (int i2 = 0; i2 < 8; ++i2)
                Vt[(dg * 8 + i2) * VLD + j] = (unsigned short)vv[i2];
        }
        __syncthreads();

        f32x4 sacc[4];
        #pragma unroll
        for (int jc = 0; jc < 4; ++jc) {
            sacc[jc] = (f32x4){0.f, 0.f, 0.f, 0.f};
            #pragma unroll
            for (int dc = 0; dc < 4; ++dc) {
                bf16x8 bf = *(const bf16x8*)&Ks[(jc * 16 + lc) * KLD + dc * 32 + g * 8];
                sacc[jc] = __builtin_amdgcn_mfma_f32_16x16x32_bf16(qf[dc], bf, sacc[jc], 0, 0, 0);
            }
        }

        if (jt == qt) {
            const int qi = q0 + w * 16 + g * 4;
            #pragma unroll
            for (int jc = 0; jc < 4; ++jc) {
                const int jj = j0 + jc * 16 + lc;
                #pragma unroll
                for (int r = 0; r < 4; ++r)
                    if (qi + r < jj) sacc[jc][r] = -1e30f;
            }
        }

        #pragma unroll
        for (int r = 0; r < 4; ++r) {
            float tmax = fmaxf(fmaxf(sacc[0][r], sacc[1][r]), fmaxf(sacc[2][r], sacc[3][r]));
            #pragma unroll
            for (int off = 1; off < 16; off <<= 1)
                tmax = fmaxf(tmax, __shfl_xor(tmax, off));
            const float mn = fmaxf(m_r[r], tmax);
            const float alpha = __expf(m_r[r] - mn);
            m_r[r] = mn;
            float rs = 0.f;
            #pragma unroll
            for (int jc = 0; jc < 4; ++jc) {
                const float p = __expf(sacc[jc][r] - mn);
                sacc[jc][r] = p;
                rs += p;
            }
            #pragma unroll
            for (int off = 1; off < 16; off <<= 1)
                rs += __shfl_xor(rs, off);
            l_r[r] = l_r[r] * alpha + rs;
            #pragma unroll
            for (int dc8 = 0; dc8 < 8; ++dc8)
                oacc[dc8][r] *= alpha;
        }

        unsigned short* pw = Ps[w];
        #pragma unroll
        for (int jc = 0; jc < 4; ++jc)
            #pragma unroll
            for (int r = 0; r < 4; ++r)
                pw[(g * 4 + r) * PLD + jc * 16 + lc] = f2bf(sacc[jc][r]);

        __asm__ volatile("s_waitcnt lgkmcnt(0)" ::: "memory");

        bf16x8 pa[2];
        #pragma unroll
        for (int jc2 = 0; jc2 < 2; ++jc2)
            pa[jc2] = *(const bf16x8*)&pw[lc * PLD + jc2 * 32 + g * 8];

        #pragma unroll
        for (int dc8 = 0; dc8 < 8; ++dc8) {
            #pragma unroll
            for (int jc2 = 0; jc2 < 2; ++jc2) {
                bf16x8 bv = *(const bf16x8*)&Vt[(dc8 * 16 + lc) * VLD + jc2 * 32 + g * 8];
                oacc[dc8] = __builtin_amdgcn_mfma_f32_16x16x32_bf16(pa[jc2], bv, oacc[dc8], 0, 0, 0);
            }
        }
        __syncthreads();
    }

    #pragma unroll
    for (int r = 0; r < 4; ++r) {
        const float inv = 1.0f / l_r[r];
        unsigned short* op = o + bhbase + (size_t)(q0 + w * 16 + g * 4 + r) * 1024 + lc;
        #pragma unroll
        for (int dc8 = 0; dc8 < 8; ++dc8)
            op[dc8 * 16] = f2bf(oacc[dc8][r] * inv);
    }
}

// ---------------------------------------------------------------------------
extern "C" void kernel_launch(void* const* d_in, const int* in_sizes, int n_in,
                              void* d_out, int out_size, void* d_ws, size_t ws_size,
                              hipStream_t stream)
{
    const float* x  = (const float*)d_in[0];   // [4096,1024]
    const float* wq = (const float*)d_in[1];
    const float* wk = (const float*)d_in[2];
    const float* wv = (const float*)d_in[3];
    const float* wo = (const float*)d_in[4];
    float* out = (float*)d_out;

    const size_t SZ = (size_t)NROW * HD;               // 4M elements
    unsigned short* qb    = (unsigned short*)d_ws;     // 8 MB
    unsigned short* kb    = qb + SZ;                   // 8 MB
    unsigned short* vb    = kb + SZ;                   // 8 MB
    unsigned short* ob    = vb + SZ;                   // 8 MB
    unsigned short* xb    = ob + SZ;                   // 8 MB
    unsigned short* wqkvT = xb + SZ;                   // 6 MB  [3072][1024]
    unsigned short* woT   = wqkvT + 3 * 1024 * 1024;   // 2 MB  [1024][1024]

    // prologue: casts + weight transposes
    cast_bf16<<<SZ / (256 * 4), 256, 0, stream>>>(x, xb);
    transpose_cast<<<dim3(32, 32), 256, 0, stream>>>(wq, wqkvT);
    transpose_cast<<<dim3(32, 32), 256, 0, stream>>>(wk, wqkvT + 1024 * 1024);
    transpose_cast<<<dim3(32, 32), 256, 0, stream>>>(wv, wqkvT + 2 * 1024 * 1024);
    transpose_cast<<<dim3(32, 32), 256, 0, stream>>>(wo, woT);

    // fused QKV projection: [4096x1024] x [1024x3072] -> q,k,v bf16
    gemm_bt<0><<<dim3(24, 32), 256, 0, stream>>>(xb, wqkvT, qb, kb, vb, nullptr);

    rmsnorm_rope_bf16<<<dim3(NROW * H_, 2), 64, 0, stream>>>(qb, kb);

    flash_attn<<<dim3(B_ * H_, 32), 256, 0, stream>>>(qb, kb, vb, ob);

    // output projection: [4096x1024] x [1024x1024] -> fp32 out
    gemm_bt<1><<<dim3(8, 32), 256, 0, stream>>>(ob, woT, nullptr, nullptr, nullptr, out);
}

// Round 4
// 209.159 us; speedup vs baseline: 14.5371x; 1.1934x over previous
//
#include <hip/hip_runtime.h>
#include <hip/hip_bf16.h>
#include <math.h>

// Problem constants: B=2, T=2048, M=1024, H=8, D=128
#define B_  2
#define T_  2048
#define M_  1024
#define H_  8
#define D_  128
#define NROW (B_ * T_)          // 4096
#define HD  (H_ * D_)           // 1024

#define NORM_EPS 1e-6f
#define QK_MULT  0.08838834764831845f   // sqrt(1/128)
#define ROT_BASE 10000.0f

typedef short bf16x8 __attribute__((ext_vector_type(8)));   // 8 bf16 = 4 VGPRs
typedef float f32x4  __attribute__((ext_vector_type(4)));

static __device__ __forceinline__ unsigned short f2bf(float f) {
    union { __hip_bfloat16 h; unsigned short u; } cv;
    cv.h = __float2bfloat16(f);
    return cv.u;
}
static __device__ __forceinline__ float bf2f(unsigned short u) {
    union { unsigned short u; __hip_bfloat16 h; } cv;
    cv.u = u;
    return __bfloat162float(cv.h);
}

// async global->LDS, 16 bytes per lane. LDS dest = wave-uniform base + lane*16.
static __device__ __forceinline__ void gload_lds16(const unsigned short* g,
                                                   unsigned short* l) {
    __builtin_amdgcn_global_load_lds(
        (const __attribute__((address_space(1))) void*)g,
        (__attribute__((address_space(3))) void*)l, 16, 0, 0);
}

// ---------------------------------------------------------------------------
// cast fp32 -> bf16, 4 elements/thread
// ---------------------------------------------------------------------------
__global__ __launch_bounds__(256) void cast_bf16(const float* __restrict__ in,
                                                 unsigned short* __restrict__ out)
{
    const int i = (blockIdx.x * 256 + threadIdx.x) * 4;
    const float4 v = *(const float4*)(in + i);
    ushort4 o;
    o.x = f2bf(v.x); o.y = f2bf(v.y); o.z = f2bf(v.z); o.w = f2bf(v.w);
    *(ushort4*)(out + i) = o;
}

// ---------------------------------------------------------------------------
// transpose + cast all 4 weights in one launch: out[n][k] = bf16(in[k][n])
// z selects the source; z<3 -> wqkvT + z*1M, z==3 -> woT
// ---------------------------------------------------------------------------
__global__ __launch_bounds__(256) void transpose_cast4(const float* __restrict__ w0,
                                                       const float* __restrict__ w1,
                                                       const float* __restrict__ w2,
                                                       const float* __restrict__ w3,
                                                       unsigned short* __restrict__ wqkvT,
                                                       unsigned short* __restrict__ woT)
{
    __shared__ float t[32][33];
    const int z = blockIdx.z;
    const float* in = z == 0 ? w0 : (z == 1 ? w1 : (z == 2 ? w2 : w3));
    unsigned short* out = z < 3 ? (wqkvT + (size_t)z * 1024 * 1024) : woT;

    const int tx = threadIdx.x & 31;
    const int ty = threadIdx.x >> 5;          // 0..7
    const int n0 = blockIdx.x * 32;
    const int k0 = blockIdx.y * 32;
    #pragma unroll
    for (int r = 0; r < 4; ++r)
        t[ty + r * 8][tx] = in[(size_t)(k0 + ty + r * 8) * 1024 + n0 + tx];
    __syncthreads();
    #pragma unroll
    for (int r = 0; r < 4; ++r)
        out[(size_t)(n0 + ty + r * 8) * 1024 + k0 + tx] = f2bf(t[tx][ty + r * 8]);
}

// ---------------------------------------------------------------------------
// V transpose: vb[b,t,h,d] (bf16) -> vt[(b,h),d,t] (bf16)
// ---------------------------------------------------------------------------
__global__ __launch_bounds__(256) void v_transpose(const unsigned short* __restrict__ vb,
                                                   unsigned short* __restrict__ vt)
{
    __shared__ unsigned short s[32][33];
    const int tx = threadIdx.x & 31;
    const int ty = threadIdx.x >> 5;          // 0..7
    const int t0 = blockIdx.x * 32;           // t
    const int d0 = blockIdx.y * 32;           // d within head
    const int bh = blockIdx.z;
    const int h = bh & 7, b = bh >> 3;

    #pragma unroll
    for (int r = 0; r < 4; ++r)
        s[ty + r * 8][tx] = vb[(size_t)(b * T_ + t0 + ty + r * 8) * 1024 + h * 128 + d0 + tx];
    __syncthreads();
    #pragma unroll
    for (int r = 0; r < 4; ++r)
        vt[((size_t)bh * 128 + d0 + ty + r * 8) * T_ + t0 + tx] = s[tx][ty + r * 8];
}

// ---------------------------------------------------------------------------
// bf16 MFMA GEMM (m97 structure): C[M x N] = A[M x K] * Bt[N x K]^T
// ---------------------------------------------------------------------------
template <int MODE>
__global__ __launch_bounds__(256) void gemm_bt(const unsigned short* __restrict__ A,
                                               const unsigned short* __restrict__ Bt,
                                               unsigned short* __restrict__ oq,
                                               unsigned short* __restrict__ ok,
                                               unsigned short* __restrict__ ov,
                                               float* __restrict__ cf)
{
    __shared__ unsigned short As[128 * 32];
    __shared__ unsigned short Bs[128 * 32];

    const int tid  = threadIdx.x;
    const int lane = tid & 63;
    const int w    = tid >> 6;
    const int g    = lane >> 4;
    const int lc   = lane & 15;
    const int wm   = w >> 1;
    const int wn   = w & 1;

    const int m0 = blockIdx.y * 128;
    const int n0 = blockIdx.x * 128;

    const unsigned short* aBase = A  + (size_t)m0 * 1024;
    const unsigned short* bBase = Bt + (size_t)n0 * 1024;

    f32x4 acc[4][4];
    #pragma unroll
    for (int i = 0; i < 4; ++i)
        #pragma unroll
        for (int j = 0; j < 4; ++j)
            acc[i][j] = (f32x4){0.f, 0.f, 0.f, 0.f};

    for (int kt = 0; kt < 32; ++kt) {
        const int k0 = kt * 32;
        #pragma unroll
        for (int it = 0; it < 2; ++it) {
            const int u  = tid + it * 256;      // 0..511
            const int r2 = u >> 2;              // tile row
            const int s2 = u & 3;               // 16B segment in row
            gload_lds16(aBase + (size_t)r2 * 1024 + k0 + s2 * 8, &As[u * 8]);
            gload_lds16(bBase + (size_t)r2 * 1024 + k0 + s2 * 8, &Bs[u * 8]);
        }
        __syncthreads();

        bf16x8 af[4], bfr[4];
        #pragma unroll
        for (int i = 0; i < 4; ++i)
            af[i] = *(const bf16x8*)&As[(wm * 64 + i * 16 + lc) * 32 + g * 8];
        #pragma unroll
        for (int j = 0; j < 4; ++j)
            bfr[j] = *(const bf16x8*)&Bs[(wn * 64 + j * 16 + lc) * 32 + g * 8];

        #pragma unroll
        for (int i = 0; i < 4; ++i)
            #pragma unroll
            for (int j = 0; j < 4; ++j)
                acc[i][j] = __builtin_amdgcn_mfma_f32_16x16x32_bf16(af[i], bfr[j], acc[i][j], 0, 0, 0);
        __syncthreads();
    }

    if (MODE == 0) {
        const int which = n0 >> 10;
        unsigned short* outp = which == 0 ? oq : (which == 1 ? ok : ov);
        const int ncol0 = (n0 & 1023) + wn * 64;
        #pragma unroll
        for (int i = 0; i < 4; ++i) {
            const int mrow = m0 + wm * 64 + i * 16 + g * 4;
            #pragma unroll
            for (int j = 0; j < 4; ++j) {
                const int nc = ncol0 + j * 16 + lc;
                #pragma unroll
                for (int r = 0; r < 4; ++r)
                    outp[(size_t)(mrow + r) * 1024 + nc] = f2bf(acc[i][j][r]);
            }
        }
    } else {
        #pragma unroll
        for (int i = 0; i < 4; ++i) {
            const int mrow = m0 + wm * 64 + i * 16 + g * 4;
            #pragma unroll
            for (int j = 0; j < 4; ++j) {
                const int nc = n0 + wn * 64 + j * 16 + lc;
                #pragma unroll
                for (int r = 0; r < 4; ++r)
                    cf[(size_t)(mrow + r) * 1024 + nc] = acc[i][j][r];
            }
        }
    }
}

// ---------------------------------------------------------------------------
// Fused RMSNorm + RoPE + sqrt(qk_scale), bf16 in-place. 4 waves / block,
// one wave per (b,t,h) vector.
// ---------------------------------------------------------------------------
__global__ __launch_bounds__(256) void rmsnorm_rope_bf16(unsigned short* __restrict__ q,
                                                         unsigned short* __restrict__ k)
{
    const int vec = blockIdx.x * 4 + (threadIdx.x >> 6);   // (b*T + t)*H + h
    unsigned short* p = (blockIdx.y == 0 ? q : k) + (size_t)vec * 128;
    const int t = (vec / H_) % T_;
    const int lane = threadIdx.x & 63;

    float e = bf2f(p[lane]);
    float o = bf2f(p[lane + 64]);
    float ss = e * e + o * o;
    #pragma unroll
    for (int off = 32; off; off >>= 1) ss += __shfl_xor(ss, off);
    const float r = rsqrtf(ss * (1.0f / 128.0f) + NORM_EPS) * QK_MULT;
    e *= r;
    o *= r;

    const float freq = expf(-(float)lane * (logf(ROT_BASE) / 64.0f));
    const float rad = (float)t * freq;
    const float c = cosf(rad);
    const float s = sinf(rad);

    p[lane]      = f2bf(e * c - o * s);
    p[lane + 64] = f2bf(e * s + o * c);
}

// ---------------------------------------------------------------------------
// Flash attention v2. One 256-thr block per (b,h, q-tile 64).
// Key insight: after RMSNorm+scale, |q|=|k|=1 => s = q.k in [-1,1], so
// softmax uses a FIXED shift (exp(s) directly): no running max, no rescale,
// no in-loop reductions. l accumulated lane-locally, reduced in epilogue.
// K and V^T staged via async global_load_lds into XOR-swizzled unpadded LDS
// (chunk c stored at c ^ (row & mask)), double-buffered.
// ---------------------------------------------------------------------------
#define PLD 72    // P tile leading dim (padded, plain ds ops)

__global__ __launch_bounds__(256) void flash_attn(const unsigned short* __restrict__ qb,
                                                  const unsigned short* __restrict__ kb,
                                                  const unsigned short* __restrict__ vt,
                                                  unsigned short* __restrict__ o)
{
    __shared__ unsigned short Ks[2][64 * 128];    // [j][16B-chunk swizzled]
    __shared__ unsigned short Vs[2][128 * 64];    // [d][chunk swizzled]
    __shared__ unsigned short Ps[4][16 * PLD];    // per-wave P tile

    const int tid  = threadIdx.x;
    const int lane = tid & 63;
    const int w    = tid >> 6;
    const int g    = lane >> 4;
    const int lc   = lane & 15;

    const int bh = blockIdx.x;          // b*H + h
    const int h  = bh & (H_ - 1);
    const int b  = bh >> 3;
    const int yy = blockIdx.y;
    const int qt = (yy & 1) ? (31 - (yy >> 1)) : (yy >> 1);   // causal balance
    const int q0 = qt * 64;

    const size_t bhbase  = (size_t)b * T_ * HD + (size_t)h * 128;   // q,k,o
    const size_t bhvbase = (size_t)bh * 128 * T_;                   // vt

    // staging offsets (loop-invariant): thread stages chunks m = (w*4+it)*64+lane
    int mI[4];
    size_t srcKoff[4], srcVoff[4];
    #pragma unroll
    for (int it = 0; it < 4; ++it) {
        const int m = (w * 4 + it) * 64 + lane;
        mI[it] = m;
        const int jK = m >> 4, cK = (m & 15) ^ (jK & 15);
        srcKoff[it] = (size_t)jK * 1024 + cK * 8;
        const int dV = m >> 3, cV = (m & 7) ^ (dV & 7);
        srcVoff[it] = (size_t)dV * T_ + cV * 8;
    }
    const unsigned short* kgb = kb + bhbase;
    const unsigned short* vgb = vt + bhvbase;

    // Q fragments (A-operand)
    bf16x8 qf[4];
    {
        const unsigned short* qp = qb + bhbase + (size_t)(q0 + w * 16 + lc) * 1024 + g * 8;
        #pragma unroll
        for (int dc = 0; dc < 4; ++dc)
            qf[dc] = *(const bf16x8*)(qp + dc * 32);
    }

    float lsum[4] = {0.f, 0.f, 0.f, 0.f};
    f32x4 oacc[8];
    #pragma unroll
    for (int dc8 = 0; dc8 < 8; ++dc8) oacc[dc8] = (f32x4){0.f, 0.f, 0.f, 0.f};

    // prologue: stage tile 0 into buffer 0
    #pragma unroll
    for (int it = 0; it < 4; ++it) {
        gload_lds16(kgb + srcKoff[it], &Ks[0][mI[it] * 8]);
        gload_lds16(vgb + srcVoff[it], &Vs[0][mI[it] * 8]);
    }

    for (int jt = 0; jt <= qt; ++jt) {
        const int cur = jt & 1;
        __syncthreads();   // drains this tile's loads; frees other buffer

        if (jt < qt) {     // async-prefetch next tile during compute
            const size_t j0n = (size_t)(jt + 1) * 64;
            #pragma unroll
            for (int it = 0; it < 4; ++it) {
                gload_lds16(kgb + j0n * 1024 + srcKoff[it], &Ks[cur ^ 1][mI[it] * 8]);
                gload_lds16(vgb + j0n + srcVoff[it], &Vs[cur ^ 1][mI[it] * 8]);
            }
        }

        // --- S = Q K^T ---
        f32x4 sacc[4];
        #pragma unroll
        for (int jc = 0; jc < 4; ++jc) {
            sacc[jc] = (f32x4){0.f, 0.f, 0.f, 0.f};
            #pragma unroll
            for (int dc = 0; dc < 4; ++dc) {
                bf16x8 bf = *(const bf16x8*)&Ks[cur][(jc * 16 + lc) * 128 + (((dc * 4 + g) ^ lc) << 3)];
                sacc[jc] = __builtin_amdgcn_mfma_f32_16x16x32_bf16(qf[dc], bf, sacc[jc], 0, 0, 0);
            }
        }

        // --- causal mask on diagonal tile ---
        if (jt == qt) {
            const int qi = q0 + w * 16 + g * 4;
            #pragma unroll
            for (int jc = 0; jc < 4; ++jc) {
                const int jj = q0 + jc * 16 + lc;
                #pragma unroll
                for (int r = 0; r < 4; ++r)
                    if (qi + r < jj) sacc[jc][r] = -1e30f;
            }
        }

        // --- fixed-shift softmax: p = exp(s), s bounded by Cauchy-Schwarz ---
        #pragma unroll
        for (int jc = 0; jc < 4; ++jc)
            #pragma unroll
            for (int r = 0; r < 4; ++r) {
                const float p = __expf(sacc[jc][r]);
                sacc[jc][r] = p;
                lsum[r] += p;
            }

        // --- P (C-layout) -> LDS -> A-layout (wave-private) ---
        unsigned short* pw = Ps[w];
        #pragma unroll
        for (int jc = 0; jc < 4; ++jc)
            #pragma unroll
            for (int r = 0; r < 4; ++r)
                pw[(g * 4 + r) * PLD + jc * 16 + lc] = f2bf(sacc[jc][r]);

        __asm__ volatile("s_waitcnt lgkmcnt(0)" ::: "memory");

        bf16x8 pa[2];
        #pragma unroll
        for (int jc2 = 0; jc2 < 2; ++jc2)
            pa[jc2] = *(const bf16x8*)&pw[lc * PLD + jc2 * 32 + g * 8];

        // --- O += P V ---
        #pragma unroll
        for (int dc8 = 0; dc8 < 8; ++dc8) {
            #pragma unroll
            for (int jc2 = 0; jc2 < 2; ++jc2) {
                bf16x8 bv = *(const bf16x8*)&Vs[cur][(dc8 * 16 + lc) * 64 + (((jc2 * 4 + g) ^ (lc & 7)) << 3)];
                oacc[dc8] = __builtin_amdgcn_mfma_f32_16x16x32_bf16(pa[jc2], bv, oacc[dc8], 0, 0, 0);
            }
        }
    }

    // --- epilogue: reduce l over the 16 lanes of each row, write O bf16 ---
    #pragma unroll
    for (int r = 0; r < 4; ++r) {
        float l = lsum[r];
        #pragma unroll
        for (int off = 1; off < 16; off <<= 1) l += __shfl_xor(l, off);
        const float inv = 1.0f / l;
        unsigned short* op = o + bhbase + (size_t)(q0 + w * 16 + g * 4 + r) * 1024 + lc;
        #pragma unroll
        for (int dc8 = 0; dc8 < 8; ++dc8)
            op[dc8 * 16] = f2bf(oacc[dc8][r] * inv);
    }
}

// ---------------------------------------------------------------------------
extern "C" void kernel_launch(void* const* d_in, const int* in_sizes, int n_in,
                              void* d_out, int out_size, void* d_ws, size_t ws_size,
                              hipStream_t stream)
{
    const float* x  = (const float*)d_in[0];   // [4096,1024]
    const float* wq = (const float*)d_in[1];
    const float* wk = (const float*)d_in[2];
    const float* wv = (const float*)d_in[3];
    const float* wo = (const float*)d_in[4];
    float* out = (float*)d_out;

    const size_t SZ = (size_t)NROW * HD;               // 4M elements
    unsigned short* qb    = (unsigned short*)d_ws;     // 8 MB
    unsigned short* kb    = qb + SZ;                   // 8 MB
    unsigned short* vb    = kb + SZ;                   // 8 MB
    unsigned short* ob    = vb + SZ;                   // 8 MB
    unsigned short* xb    = ob + SZ;                   // 8 MB
    unsigned short* vt    = xb + SZ;                   // 8 MB [(b,h),d,t]
    unsigned short* wqkvT = vt + SZ;                   // 6 MB [3072][1024]
    unsigned short* woT   = wqkvT + 3 * 1024 * 1024;   // 2 MB

    // prologue casts / transposes
    cast_bf16<<<SZ / (256 * 4), 256, 0, stream>>>(x, xb);
    transpose_cast4<<<dim3(32, 32, 4), 256, 0, stream>>>(wq, wk, wv, wo, wqkvT, woT);

    // fused QKV projection
    gemm_bt<0><<<dim3(24, 32), 256, 0, stream>>>(xb, wqkvT, qb, kb, vb, nullptr);

    // V transpose for attention B-operand
    v_transpose<<<dim3(64, 4, 16), 256, 0, stream>>>(vb, vt);

    rmsnorm_rope_bf16<<<dim3(NROW * H_ / 4, 2), 256, 0, stream>>>(qb, kb);

    flash_attn<<<dim3(B_ * H_, 32), 256, 0, stream>>>(qb, kb, vt, ob);

    // output projection
    gemm_bt<1><<<dim3(8, 32), 256, 0, stream>>>(ob, woT, nullptr, nullptr, nullptr, out);
}